// Round 6
// baseline (174.334 us; speedup 1.0000x reference)
//
#include <hip/hip_runtime.h>

// Problem constants:
// inputs: (B=8, C=2, D=96, H=64, W=64) f32
// weight/bias: (F=8, C=2, d=3, h=60, w=64) f32
// out: (B=8, F=8, Dout=94, h=60, w=64) f32
#define B_ 8
#define C_ 2
#define D_ 96
#define H_ 64
#define W_ 64
#define F_ 8
#define KD 3
#define h_ 60
#define Dout_ 94
#define PLANE (h_ * W_)          // 3840 floats (weight/bias/out plane)
#define NCH (PLANE / 4)          // 960 float4 chunks
#define INCH (H_ * W_ / 4)       // 1024 float4 chunks per input plane (row = 16 f4)
#define TD 4                     // douts batched per block
#define NTILE ((Dout_ + TD - 1) / TD)  // 24

__device__ __forceinline__ void fma4(float4& a, const float4 v, const float4 g) {
    a.x += v.x * g.x; a.y += v.y * g.y;
    a.z += v.z * g.z; a.w += v.w * g.w;
}

__device__ __forceinline__ void add4(float4& a, const float4 v) {
    a.x += v.x; a.y += v.y; a.z += v.z; a.w += v.w;
}

// Horizontal 3-tap sum via lane shuffles; col4 = position 0..15 within a
// 16-lane row group. Boundary cols contribute zero. All 64 lanes must execute.
__device__ __forceinline__ float4 hsum3(float4 V, int col4) {
    const int lane = threadIdx.x & 63;
    float lw = __shfl(V.w, (lane + 63) & 63, 64);
    float rx = __shfl(V.x, (lane + 1) & 63, 64);
    if (col4 == 0) lw = 0.f;
    if (col4 == 15) rx = 0.f;
    float4 o;
    o.x = lw + V.x + V.y;
    o.y = V.x + V.y + V.z;
    o.z = V.y + V.z + V.w;
    o.w = V.z + V.w + rx;
    return o;
}

// ---------------------------------------------------------------------------
// Single fused kernel (R6). Block = (b, f, tile, half) exactly like R4, but
// S2 (vertical 5-sum of input) is rebuilt per block in LDS instead of being
// materialized in a workspace by a second kernel, and BoxBias is recomputed
// per block from the L2-resident bias planes. One launch, no workspace.
//
//  * Build phase (per c): thread = (seg = t>>4, col4) computes slab rows
//    2seg, 2seg+1 of S2 for 6 p-planes from 6 input-row loads each (rolling
//    window over the same add order as before -> identical numerics).
//    Input[b] slice = 3.1 MB -> fits the XCD-pinned L2 (b = bx&7).
//  * FMA phase (per c): thread = (lr = t>>4, col4) reads its 2 slab rows per
//    plane and accumulates acc[td] in the SAME (c-major, z-ascending) order
//    as R4. Weight reg cache 12 float4, identical to R4.
//  * Epilogue: identical to R4 (acc slab in LDS, vertical 3-tap, hsum3,
//    +bb, *0.25, leaky, plain coalesced float4 stores; NO nontemporal —
//    NT stores amplified HBM writes +52 MB in both R1 and R5).
//  * LDS: 48 KB slab (6 planes x 32 rows x 16 f4), aliased by the 32 KB
//    epilogue acc buffer -> 3 blocks/CU; __launch_bounds__(256,3) caps
//    VGPR at 170 (no R3-style spill possible).
// ---------------------------------------------------------------------------
__global__ __launch_bounds__(256, 3) void k_fused(const float* __restrict__ in,
                                                  const float* __restrict__ wt,
                                                  const float* __restrict__ bs,
                                                  float* __restrict__ out) {
    const int bx = blockIdx.x;
    const int b = bx & 7;            // XCD-pinned batch index
    const int f = (bx >> 3) & 7;
    const int half = (bx >> 6) & 1;
    const int tile = bx >> 7;        // 0..23
    const int d0 = tile * TD;
    const int t = threadIdx.x;
    const int col4 = t & 15;
    const int lr = t >> 4;           // row-group index 0..15 (also build seg)

    // acc rows (R4 halo scheme): chunk A = gbase+lr, chunk B = gA+16
    const int gbase = half * 30 - 1;      // -1 or 29
    const int gA = gbase + lr;            // [-1..45]
    const int gB = gA + 16;               // [15..60]
    const bool vA = (gA >= 0) && (gA <= h_ - 1);
    const bool vB = (gB >= 0) && (gB <= h_ - 1);
    const int cgA = min(max(gA, 0), h_ - 1);
    const int cgB = min(max(gB, 0), h_ - 1);
    const int eA = cgA * 16 + col4;       // clamped weight/bias/out chunk index
    const int eB = cgB * 16 + col4;

    __shared__ float4 SL[6 * 32 * 16];    // 48 KB: S2 slab, later acc slab

    // ---- prologue: weight reg cache (12 f4) ----
    const float4* wp = (const float4*)(wt + (size_t)f * (C_ * KD * PLANE));
    float4 wrA[6], wrB[6];
#pragma unroll
    for (int s6 = 0; s6 < 6; ++s6) {
        wrA[s6] = wp[s6 * NCH + eA];
        wrB[s6] = wp[s6 * NCH + eB];
    }

    // ---- prologue: boxed bias recomputed in-block ----
    // bb = hsum3( sum_{tap rows gX-1..gX+1, valid} sum_{s6} bias[s6][row] )
    // Same op order as the old k_prep bias path (s6-sum, then a+m+d, hsum3).
    const float4* bp = (const float4*)(bs + (size_t)f * (C_ * KD * PLANE));
    float4 bbA, bbB;
    {
        float4 VAb = make_float4(0, 0, 0, 0), VBb = make_float4(0, 0, 0, 0);
#pragma unroll
        for (int tap = 0; tap < 3; ++tap) {
            const int rrA = gA - 1 + tap;
            const int rrB = gB - 1 + tap;
            const int rcA = min(max(rrA, 0), h_ - 1);
            const int rcB = min(max(rrB, 0), h_ - 1);
            float4 sA_ = make_float4(0, 0, 0, 0);
            float4 sB_ = make_float4(0, 0, 0, 0);
#pragma unroll
            for (int s6 = 0; s6 < 6; ++s6) {
                add4(sA_, bp[s6 * NCH + rcA * 16 + col4]);
                add4(sB_, bp[s6 * NCH + rcB * 16 + col4]);
            }
            if (rrA < 0 || rrA > h_ - 1) sA_ = make_float4(0, 0, 0, 0);
            if (rrB < 0 || rrB > h_ - 1) sB_ = make_float4(0, 0, 0, 0);
            add4(VAb, sA_);
            add4(VBb, sB_);
        }
        bbA = hsum3(VAb, col4);
        bbB = hsum3(VBb, col4);
    }

    const float4* inb = (const float4*)in + (size_t)(b * C_) * D_ * INCH;
    float* ob = out + (size_t)((b * F_ + f) * Dout_) * PLANE;

    float4 accA[TD], accB[TD];
#pragma unroll
    for (int td = 0; td < TD; ++td) {
        accA[td] = make_float4(0, 0, 0, 0);
        accB[td] = make_float4(0, 0, 0, 0);
    }

    // ---- per-c: build S2 slab in LDS, then FMA ----
#pragma unroll
    for (int c = 0; c < C_; ++c) {
        // build: seg = lr owns slab rows 2*lr, 2*lr+1 (global rows g0, g0+1)
        const int g0 = gbase + 2 * lr;
#pragma unroll
        for (int pi = 0; pi < 6; ++pi) {
            int p = d0 + pi; if (p > D_ - 1) p = D_ - 1;  // tail-tile clamp
            const float4* ip = inb + (size_t)(c * D_ + p) * INCH;
            float4 v[6];
#pragma unroll
            for (int j = 0; j < 6; ++j) {
                const int rr = min(max(g0 + j, 0), H_ - 1);  // clamp: affected
                v[j] = ip[rr * 16 + col4];                   // rows are invalid-only
            }
            float4 s0 = v[0];
#pragma unroll
            for (int j = 1; j < 5; ++j) add4(s0, v[j]);      // in rows g0..g0+4
            float4 s1 = v[1];
#pragma unroll
            for (int j = 2; j < 6; ++j) add4(s1, v[j]);      // in rows g0+1..g0+5
            SL[(pi * 32 + 2 * lr) * 16 + col4] = s0;
            SL[(pi * 32 + 2 * lr + 1) * 16 + col4] = s1;
        }
        __syncthreads();

        // FMA: slab row lr (=gA) and lr+16 (=gB); z-ascending per td (R4 order)
#pragma unroll
        for (int pi = 0; pi < 6; ++pi) {
            const float4 sA_ = SL[(pi * 32 + lr) * 16 + col4];
            const float4 sB_ = SL[(pi * 32 + lr + 16) * 16 + col4];
#pragma unroll
            for (int z = 0; z < KD; ++z) {
                const int td = pi - z;
                if (td >= 0 && td < TD) {
                    fma4(accA[td], sA_, wrA[c * KD + z]);
                    fma4(accB[td], sB_, wrB[c * KD + z]);
                }
            }
        }
        __syncthreads();   // protect slab before next c overwrites / epilogue
    }

    // ---- epilogue: identical to R4, acc slab aliased into SL ----
#pragma unroll
    for (int td = 0; td < TD; ++td) {
        if (!vA) accA[td] = make_float4(0, 0, 0, 0);   // halo pad rows are zero
        if (!vB) accB[td] = make_float4(0, 0, 0, 0);
        SL[td * 512 + t] = accA[td];
        SL[td * 512 + 256 + t] = accB[td];
    }
    __syncthreads();

    const bool sA = (lr >= 1);                 // owns output row gA
    const bool sB = (lr <= 14);                // owns output row gB
    const int iuA = (lr == 0) ? t : t - 16;    // clamp (discarded anyway)
    const int idB = (lr == 15) ? t + 256 : t + 272;

#pragma unroll
    for (int td = 0; td < TD; ++td) {
        const int dout = d0 + td;
        const float4* Eb = &SL[td * 512];

        // chunk A vertical 3-tap
        const float4 uA = Eb[iuA];
        const float4 mA = Eb[t];
        const float4 dA = Eb[t + 16];          // lr=15 -> chunk B row 16: valid
        float4 VA;
        VA.x = uA.x + mA.x + dA.x; VA.y = uA.y + mA.y + dA.y;
        VA.z = uA.z + mA.z + dA.z; VA.w = uA.w + mA.w + dA.w;
        float4 rA = hsum3(VA, col4);

        // chunk B vertical 3-tap
        const float4 uB = Eb[t + 240];         // chunk A row lr+15: valid
        const float4 mB = Eb[t + 256];
        const float4 dB = Eb[idB];
        float4 VB;
        VB.x = uB.x + mB.x + dB.x; VB.y = uB.y + mB.y + dB.y;
        VB.z = uB.z + mB.z + dB.z; VB.w = uB.w + mB.w + dB.w;
        float4 rB = hsum3(VB, col4);

        rA.x = 0.25f * (rA.x + bbA.x); rA.y = 0.25f * (rA.y + bbA.y);
        rA.z = 0.25f * (rA.z + bbA.z); rA.w = 0.25f * (rA.w + bbA.w);
        rB.x = 0.25f * (rB.x + bbB.x); rB.y = 0.25f * (rB.y + bbB.y);
        rB.z = 0.25f * (rB.z + bbB.z); rB.w = 0.25f * (rB.w + bbB.w);
        rA.x = (rA.x > 0.f) ? rA.x : 0.2f * rA.x;
        rA.y = (rA.y > 0.f) ? rA.y : 0.2f * rA.y;
        rA.z = (rA.z > 0.f) ? rA.z : 0.2f * rA.z;
        rA.w = (rA.w > 0.f) ? rA.w : 0.2f * rA.w;
        rB.x = (rB.x > 0.f) ? rB.x : 0.2f * rB.x;
        rB.y = (rB.y > 0.f) ? rB.y : 0.2f * rB.y;
        rB.z = (rB.z > 0.f) ? rB.z : 0.2f * rB.z;
        rB.w = (rB.w > 0.f) ? rB.w : 0.2f * rB.w;

        if (dout < Dout_) {
            float4* od4 = (float4*)(ob + (size_t)dout * PLANE);
            if (sA) od4[gA * 16 + col4] = rA;
            if (sB) od4[gB * 16 + col4] = rB;
        }
    }
}

extern "C" void kernel_launch(void* const* d_in, const int* in_sizes, int n_in,
                              void* d_out, int out_size, void* d_ws, size_t ws_size,
                              hipStream_t stream) {
    const float* in = (const float*)d_in[0];
    const float* wt = (const float*)d_in[1];
    const float* bs = (const float*)d_in[2];
    float* out = (float*)d_out;
    (void)d_ws; (void)ws_size;   // single-launch: no workspace round-trip

    k_fused<<<dim3(B_ * F_ * NTILE * 2), dim3(256), 0, stream>>>(in, wt, bs, out);
}

// Round 7
// 134.850 us; speedup vs baseline: 1.2928x; 1.2928x over previous
//
#include <hip/hip_runtime.h>

// Problem constants:
// inputs: (B=8, C=2, D=96, H=64, W=64) f32
// weight/bias: (F=8, C=2, d=3, h=60, w=64) f32
// out: (B=8, F=8, Dout=94, h=60, w=64) f32
#define B_ 8
#define C_ 2
#define D_ 96
#define H_ 64
#define W_ 64
#define F_ 8
#define KD 3
#define h_ 60
#define Dout_ 94
#define PLANE (h_ * W_)          // 3840 floats
#define NCH (PLANE / 4)          // 960 float4 chunks
#define TD 4                     // douts batched per block (ONE barrier per batch)
#define NTILE ((Dout_ + TD - 1) / TD)  // 24
#define NS2 (B_ * C_ * D_)       // 1536 s2 planes
#define S2_FLOATS ((size_t)NS2 * PLANE)

__device__ __forceinline__ void fma4(float4& a, const float4 v, const float4 g) {
    a.x += v.x * g.x; a.y += v.y * g.y;
    a.z += v.z * g.z; a.w += v.w * g.w;
}

__device__ __forceinline__ void add4(float4& a, const float4 v) {
    a.x += v.x; a.y += v.y; a.z += v.z; a.w += v.w;
}

// Horizontal 3-tap sum via lane shuffles; col4 = position 0..15 within a
// 16-lane row group. Boundary cols contribute zero. All 64 lanes must execute.
__device__ __forceinline__ float4 hsum3(float4 V, int col4) {
    const int lane = threadIdx.x & 63;
    float lw = __shfl(V.w, (lane + 63) & 63, 64);
    float rx = __shfl(V.x, (lane + 1) & 63, 64);
    if (col4 == 0) lw = 0.f;
    if (col4 == 15) rx = 0.f;
    float4 o;
    o.x = lw + V.x + V.y;
    o.y = V.x + V.y + V.z;
    o.z = V.y + V.z + V.w;
    o.w = V.z + V.w + rx;
    return o;
}

// ---------------------------------------------------------------------------
// Prep kernel (R5 version: barrier-free S2 path, proven in R5).
// Blocks 0..NS2-1: S2[b,c,p] = vertical 5-sum of input plane (no LDS/barrier).
// Blocks NS2..NS2+F_-1: BoxBS[f] = Box3x3( sum_{c,z} bias[f,c,z] ).
// ---------------------------------------------------------------------------
__global__ __launch_bounds__(256) void k_prep(const float* __restrict__ in,
                                              const float* __restrict__ bs,
                                              float* __restrict__ s2,
                                              float* __restrict__ bb) {
    const int bx = blockIdx.x;
    const int tid = threadIdx.x;
    __shared__ float4 lds[H_ * 16];  // used by bias path only (16 KB)

    if (bx < NS2) {
        const int col4 = tid & 15;
        const int seg = tid >> 4;         // 0..15; seg 15 idle (15*4 = 60 rows)
        if (seg >= 15) return;
        const int r0 = seg * 4;
        const float4* ip4 = (const float4*)(in + (size_t)bx * (H_ * W_));
        float4* op4 = (float4*)(s2 + (size_t)bx * PLANE);
        float4 v[8];
#pragma unroll
        for (int j = 0; j < 8; ++j) v[j] = ip4[(r0 + j) * 16 + col4];
#pragma unroll
        for (int r = 0; r < 4; ++r) {
            float4 s = v[r];
#pragma unroll
            for (int j = 1; j < 5; ++j) add4(s, v[r + j]);
            op4[(r0 + r) * 16 + col4] = s;
        }
    } else {
        const int f = bx - NS2;
        float4* R = lds;  // rows 0..61, rows 0 and 61 zero
        if (tid < 32) {
            const int r = (tid >> 4) ? 61 : 0;
            R[r * 16 + (tid & 15)] = make_float4(0, 0, 0, 0);
        }
        const float4* bp = (const float4*)(bs + (size_t)f * (C_ * KD * PLANE));
#pragma unroll
        for (int k = 0; k < 4; ++k) {
            const int e = tid + 256 * k;
            if (e < NCH) {
                float4 s = make_float4(0, 0, 0, 0);
#pragma unroll
                for (int s6 = 0; s6 < 6; ++s6) add4(s, bp[s6 * NCH + e]);
                R[((e >> 4) + 1) * 16 + (e & 15)] = s;
            }
        }
        __syncthreads();
        float4* ob = (float4*)(bb + (size_t)f * PLANE);
#pragma unroll
        for (int k = 0; k < 4; ++k) {
            const int e = tid + 256 * k;
            if (e < NCH) {
                const int row = e >> 4, c4 = e & 15;
                const float4 a = R[row * 16 + c4];
                const float4 m = R[(row + 1) * 16 + c4];
                const float4 d = R[(row + 2) * 16 + c4];
                float4 V;
                V.x = a.x + m.x + d.x; V.y = a.y + m.y + d.y;
                V.z = a.z + m.z + d.z; V.w = a.w + m.w + d.w;
                ob[e] = hsum3(V, c4);
            }
        }
    }
}

// ---------------------------------------------------------------------------
// Main kernel (R7 = R4 + plane-major accumulation).
//  * Block = (b, f, tile, half); half owns 30 output rows, computes 32 acc
//    rows (1-row halo); 4 independent blocks/CU; ONE barrier per block.
//  * R7 change: iterate the 6 DISTINCT (c-local) S2 planes, load each once,
//    scatter-FMA into acc[td = pi - z]. Loads: 24/thread (was 48) -> L2
//    request traffic halves (~600 -> ~300 MB). Per-accumulator FP-op order
//    is identical to R4 (c0z0,c0z1,c0z2,c1z0,...) -> bit-identical numerics.
//  * Epilogue verbatim from R4 (LDS slab, vertical 3-tap with LDS middle,
//    hsum3, +bb, *0.25, leaky, plain coalesced float4 stores — NO
//    nontemporal: NT amplified HBM writes +52 MB in both R1 and R5).
//  * Regs: acc 32 + wreg 48 + bb 8 + addr (~110 est) < 128 cap of
//    __launch_bounds__(256,4); R6 compiled the same acc+wreg set to 84 VGPR.
// ---------------------------------------------------------------------------
__global__ __launch_bounds__(256, 4) void k_main(const float* __restrict__ s2,
                                                 const float* __restrict__ wt,
                                                 const float* __restrict__ bb,
                                                 float* __restrict__ out) {
    const int bx = blockIdx.x;
    const int b = bx & 7;            // XCD-pinned batch index
    const int f = (bx >> 3) & 7;
    const int half = (bx >> 6) & 1;
    const int tile = bx >> 7;        // 0..23
    const int d0 = tile * TD;
    const int t = threadIdx.x;
    const int col4 = t & 15;
    const int lr = t >> 4;           // local row 0..15

    // global acc rows: chunk A = gbase+lr, chunk B = gbase+lr+16
    const int gbase = half * 30 - 1;      // -1 or 29
    const int gA = gbase + lr;            // [-1..45]
    const int gB = gA + 16;               // [15..60]
    const bool vA = (gA >= 0) && (gA <= h_ - 1);
    const bool vB = (gB >= 0) && (gB <= h_ - 1);
    const int cgA = min(max(gA, 0), h_ - 1);
    const int cgB = min(max(gB, 0), h_ - 1);
    const int eA = cgA * 16 + col4;       // clamped plane chunk index
    const int eB = cgB * 16 + col4;

    __shared__ float4 Lds[TD][512];       // 32 KB

    // loop-invariant caches: weights 12 float4 (48 regs) + boxed bias (8 regs)
    const float4* wp = (const float4*)(wt + (size_t)f * (C_ * KD * PLANE));
    const float4* bbp = (const float4*)(bb + (size_t)f * PLANE);
    float4 wrA[6], wrB[6];
#pragma unroll
    for (int s6 = 0; s6 < 6; ++s6) {
        wrA[s6] = wp[s6 * NCH + eA];
        wrB[s6] = wp[s6 * NCH + eB];
    }
    const float4 bbA = bbp[eA];
    const float4 bbB = bbp[eB];

    const float4* s2b = (const float4*)s2 + (size_t)(b * C_) * D_ * NCH;
    float* ob = out + (size_t)((b * F_ + f) * Dout_) * PLANE;

    // ---- phase 1 (R7): plane-major accumulation, each plane loaded ONCE ----
    float4 accA[TD], accB[TD];
#pragma unroll
    for (int td = 0; td < TD; ++td) {
        accA[td] = make_float4(0, 0, 0, 0);
        accB[td] = make_float4(0, 0, 0, 0);
    }

#pragma unroll
    for (int c = 0; c < C_; ++c)
#pragma unroll
        for (int pi = 0; pi < TD + 2; ++pi) {
            int p = d0 + pi;
            if (p > D_ - 1) p = D_ - 1;   // clamped planes feed only discarded
            const float4* sp = s2b + (size_t)(c * D_ + p) * NCH;  // tail douts
            const float4 sAv = sp[eA];
            const float4 sBv = sp[eB];
#pragma unroll
            for (int z = 0; z < KD; ++z) {
                const int td = pi - z;
                if (td >= 0 && td < TD) {
                    fma4(accA[td], sAv, wrA[c * KD + z]);
                    fma4(accB[td], sBv, wrB[c * KD + z]);
                }
            }
        }

#pragma unroll
    for (int td = 0; td < TD; ++td) {
        if (!vA) accA[td] = make_float4(0, 0, 0, 0);   // halo pad rows are zero
        if (!vB) accB[td] = make_float4(0, 0, 0, 0);
        Lds[td][t] = accA[td];        // local chunk A = lr*16+col4 = t
        Lds[td][t + 256] = accB[td];  // local chunk B
    }
    __syncthreads();   // the ONE barrier per block

    // ---- phase 2: TD epilogues (verbatim R4) ----
    const bool sA = (lr >= 1);                 // owns output row gA
    const bool sB = (lr <= 14);                // owns output row gB
    const int iuA = (lr == 0) ? t : t - 16;    // clamp (discarded anyway)
    const int idB = (lr == 15) ? t + 256 : t + 272;
    const int oA = gA * 16 + col4;
    const int oB = gB * 16 + col4;

#pragma unroll
    for (int td = 0; td < TD; ++td) {
        const int dout = d0 + td;

        // chunk A vertical 3-tap
        const float4 uA = Lds[td][iuA];
        const float4 mA = Lds[td][t];
        const float4 dA = Lds[td][t + 16];     // lr=15 -> chunk B row 16: valid
        float4 VA;
        VA.x = uA.x + mA.x + dA.x; VA.y = uA.y + mA.y + dA.y;
        VA.z = uA.z + mA.z + dA.z; VA.w = uA.w + mA.w + dA.w;
        float4 rA = hsum3(VA, col4);

        // chunk B vertical 3-tap
        const float4 uB = Lds[td][t + 240];    // chunk A row lr+15: valid
        const float4 mB = Lds[td][t + 256];
        const float4 dB = Lds[td][idB];
        float4 VB;
        VB.x = uB.x + mB.x + dB.x; VB.y = uB.y + mB.y + dB.y;
        VB.z = uB.z + mB.z + dB.z; VB.w = uB.w + mB.w + dB.w;
        float4 rB = hsum3(VB, col4);

        rA.x = 0.25f * (rA.x + bbA.x); rA.y = 0.25f * (rA.y + bbA.y);
        rA.z = 0.25f * (rA.z + bbA.z); rA.w = 0.25f * (rA.w + bbA.w);
        rB.x = 0.25f * (rB.x + bbB.x); rB.y = 0.25f * (rB.y + bbB.y);
        rB.z = 0.25f * (rB.z + bbB.z); rB.w = 0.25f * (rB.w + bbB.w);
        rA.x = (rA.x > 0.f) ? rA.x : 0.2f * rA.x;
        rA.y = (rA.y > 0.f) ? rA.y : 0.2f * rA.y;
        rA.z = (rA.z > 0.f) ? rA.z : 0.2f * rA.z;
        rA.w = (rA.w > 0.f) ? rA.w : 0.2f * rA.w;
        rB.x = (rB.x > 0.f) ? rB.x : 0.2f * rB.x;
        rB.y = (rB.y > 0.f) ? rB.y : 0.2f * rB.y;
        rB.z = (rB.z > 0.f) ? rB.z : 0.2f * rB.z;
        rB.w = (rB.w > 0.f) ? rB.w : 0.2f * rB.w;

        if (dout < Dout_) {
            float4* od4 = (float4*)(ob + (size_t)dout * PLANE);
            if (sA) od4[oA] = rA;
            if (sB) od4[oB] = rB;
        }
    }
}

extern "C" void kernel_launch(void* const* d_in, const int* in_sizes, int n_in,
                              void* d_out, int out_size, void* d_ws, size_t ws_size,
                              hipStream_t stream) {
    const float* in = (const float*)d_in[0];
    const float* wt = (const float*)d_in[1];
    const float* bs = (const float*)d_in[2];
    float* out = (float*)d_out;

    float* s2 = (float*)d_ws;
    float* bb = s2 + S2_FLOATS;

    k_prep<<<dim3(NS2 + F_), dim3(256), 0, stream>>>(in, bs, s2, bb);
    k_main<<<dim3(B_ * F_ * NTILE * 2), dim3(256), 0, stream>>>(s2, wt, bb, out);
}

// Round 8
// 131.910 us; speedup vs baseline: 1.3216x; 1.0223x over previous
//
#include <hip/hip_runtime.h>

// Problem constants:
// inputs: (B=8, C=2, D=96, H=64, W=64) f32
// weight/bias: (F=8, C=2, d=3, h=60, w=64) f32
// out: (B=8, F=8, Dout=94, h=60, w=64) f32
#define B_ 8
#define C_ 2
#define D_ 96
#define H_ 64
#define W_ 64
#define F_ 8
#define KD 3
#define h_ 60
#define Dout_ 94
#define PLANE (h_ * W_)          // 3840 floats
#define NCH (PLANE / 4)          // 960 float4 chunks
#define TD 4                     // douts batched per block (ONE barrier per batch)
#define NTILE ((Dout_ + TD - 1) / TD)  // 24
#define NS2 (B_ * C_ * D_)       // 1536 s2 planes
#define S2_FLOATS ((size_t)NS2 * PLANE)

__device__ __forceinline__ void fma4(float4& a, const float4 v, const float4 g) {
    a.x += v.x * g.x; a.y += v.y * g.y;
    a.z += v.z * g.z; a.w += v.w * g.w;
}

__device__ __forceinline__ void add4(float4& a, const float4 v) {
    a.x += v.x; a.y += v.y; a.z += v.z; a.w += v.w;
}

// Horizontal 3-tap sum via lane shuffles; col4 = position 0..15 within a
// 16-lane row group. Boundary cols contribute zero. All 64 lanes must execute.
__device__ __forceinline__ float4 hsum3(float4 V, int col4) {
    const int lane = threadIdx.x & 63;
    float lw = __shfl(V.w, (lane + 63) & 63, 64);
    float rx = __shfl(V.x, (lane + 1) & 63, 64);
    if (col4 == 0) lw = 0.f;
    if (col4 == 15) rx = 0.f;
    float4 o;
    o.x = lw + V.x + V.y;
    o.y = V.x + V.y + V.z;
    o.z = V.y + V.z + V.w;
    o.w = V.z + V.w + rx;
    return o;
}

// ---------------------------------------------------------------------------
// Prep kernel (R5 version: barrier-free S2 path, proven).
// Blocks 0..NS2-1: S2[b,c,p] = vertical 5-sum of input plane (no LDS/barrier).
// Blocks NS2..NS2+F_-1: BoxBS[f] = Box3x3( sum_{c,z} bias[f,c,z] ).
// ---------------------------------------------------------------------------
__global__ __launch_bounds__(256) void k_prep(const float* __restrict__ in,
                                              const float* __restrict__ bs,
                                              float* __restrict__ s2,
                                              float* __restrict__ bb) {
    const int bx = blockIdx.x;
    const int tid = threadIdx.x;
    __shared__ float4 lds[H_ * 16];  // used by bias path only (16 KB)

    if (bx < NS2) {
        const int col4 = tid & 15;
        const int seg = tid >> 4;         // 0..15; seg 15 idle (15*4 = 60 rows)
        if (seg >= 15) return;
        const int r0 = seg * 4;
        const float4* ip4 = (const float4*)(in + (size_t)bx * (H_ * W_));
        float4* op4 = (float4*)(s2 + (size_t)bx * PLANE);
        float4 v[8];
#pragma unroll
        for (int j = 0; j < 8; ++j) v[j] = ip4[(r0 + j) * 16 + col4];
#pragma unroll
        for (int r = 0; r < 4; ++r) {
            float4 s = v[r];
#pragma unroll
            for (int j = 1; j < 5; ++j) add4(s, v[r + j]);
            op4[(r0 + r) * 16 + col4] = s;
        }
    } else {
        const int f = bx - NS2;
        float4* R = lds;  // rows 0..61, rows 0 and 61 zero
        if (tid < 32) {
            const int r = (tid >> 4) ? 61 : 0;
            R[r * 16 + (tid & 15)] = make_float4(0, 0, 0, 0);
        }
        const float4* bp = (const float4*)(bs + (size_t)f * (C_ * KD * PLANE));
#pragma unroll
        for (int k = 0; k < 4; ++k) {
            const int e = tid + 256 * k;
            if (e < NCH) {
                float4 s = make_float4(0, 0, 0, 0);
#pragma unroll
                for (int s6 = 0; s6 < 6; ++s6) add4(s, bp[s6 * NCH + e]);
                R[((e >> 4) + 1) * 16 + (e & 15)] = s;
            }
        }
        __syncthreads();
        float4* ob = (float4*)(bb + (size_t)f * PLANE);
#pragma unroll
        for (int k = 0; k < 4; ++k) {
            const int e = tid + 256 * k;
            if (e < NCH) {
                const int row = e >> 4, c4 = e & 15;
                const float4 a = R[row * 16 + c4];
                const float4 m = R[(row + 1) * 16 + c4];
                const float4 d = R[(row + 2) * 16 + c4];
                float4 V;
                V.x = a.x + m.x + d.x; V.y = a.y + m.y + d.y;
                V.z = a.z + m.z + d.z; V.w = a.w + m.w + d.w;
                ob[e] = hsum3(V, c4);
            }
        }
    }
}

// ---------------------------------------------------------------------------
// Main kernel (R8 = R7 + 5 blocks/CU).
//  * R7 compiled to VGPR=84 / LDS=32768 B: both admit 5 blocks/CU
//    (5 x 32 KB = 160 KB = full LDS; VGPR cap at (256,5) is 102 > 84, so no
//    spill). __launch_bounds__(256,5) -> 20 waves/CU (+25% latency hiding,
//    +25% independent barrier-drain pipelines). Single change vs R7.
//  * Plane-major accumulation: 6 distinct planes per c loaded ONCE each,
//    scatter-FMA into acc[td = pi - z]; per-accumulator FP-op order identical
//    to R4 (c0z0,c0z1,c0z2,c1z0,...) -> bit-identical numerics.
//  * Epilogue verbatim R4 (LDS slab, vertical 3-tap, hsum3, +bb, *0.25,
//    leaky, plain coalesced float4 stores — NO nontemporal: NT amplified
//    HBM writes +52 MB in both R1 and R5).
// ---------------------------------------------------------------------------
__global__ __launch_bounds__(256, 5) void k_main(const float* __restrict__ s2,
                                                 const float* __restrict__ wt,
                                                 const float* __restrict__ bb,
                                                 float* __restrict__ out) {
    const int bx = blockIdx.x;
    const int b = bx & 7;            // XCD-pinned batch index
    const int f = (bx >> 3) & 7;
    const int half = (bx >> 6) & 1;
    const int tile = bx >> 7;        // 0..23
    const int d0 = tile * TD;
    const int t = threadIdx.x;
    const int col4 = t & 15;
    const int lr = t >> 4;           // local row 0..15

    // global acc rows: chunk A = gbase+lr, chunk B = gbase+lr+16
    const int gbase = half * 30 - 1;      // -1 or 29
    const int gA = gbase + lr;            // [-1..45]
    const int gB = gA + 16;               // [15..60]
    const bool vA = (gA >= 0) && (gA <= h_ - 1);
    const bool vB = (gB >= 0) && (gB <= h_ - 1);
    const int cgA = min(max(gA, 0), h_ - 1);
    const int cgB = min(max(gB, 0), h_ - 1);
    const int eA = cgA * 16 + col4;       // clamped plane chunk index
    const int eB = cgB * 16 + col4;

    __shared__ float4 Lds[TD][512];       // 32 KB

    // loop-invariant caches: weights 12 float4 (48 regs) + boxed bias (8 regs)
    const float4* wp = (const float4*)(wt + (size_t)f * (C_ * KD * PLANE));
    const float4* bbp = (const float4*)(bb + (size_t)f * PLANE);
    float4 wrA[6], wrB[6];
#pragma unroll
    for (int s6 = 0; s6 < 6; ++s6) {
        wrA[s6] = wp[s6 * NCH + eA];
        wrB[s6] = wp[s6 * NCH + eB];
    }
    const float4 bbA = bbp[eA];
    const float4 bbB = bbp[eB];

    const float4* s2b = (const float4*)s2 + (size_t)(b * C_) * D_ * NCH;
    float* ob = out + (size_t)((b * F_ + f) * Dout_) * PLANE;

    // ---- phase 1: plane-major accumulation, each plane loaded ONCE ----
    float4 accA[TD], accB[TD];
#pragma unroll
    for (int td = 0; td < TD; ++td) {
        accA[td] = make_float4(0, 0, 0, 0);
        accB[td] = make_float4(0, 0, 0, 0);
    }

#pragma unroll
    for (int c = 0; c < C_; ++c)
#pragma unroll
        for (int pi = 0; pi < TD + 2; ++pi) {
            int p = d0 + pi;
            if (p > D_ - 1) p = D_ - 1;   // clamped planes feed only discarded
            const float4* sp = s2b + (size_t)(c * D_ + p) * NCH;  // tail douts
            const float4 sAv = sp[eA];
            const float4 sBv = sp[eB];
#pragma unroll
            for (int z = 0; z < KD; ++z) {
                const int td = pi - z;
                if (td >= 0 && td < TD) {
                    fma4(accA[td], sAv, wrA[c * KD + z]);
                    fma4(accB[td], sBv, wrB[c * KD + z]);
                }
            }
        }

#pragma unroll
    for (int td = 0; td < TD; ++td) {
        if (!vA) accA[td] = make_float4(0, 0, 0, 0);   // halo pad rows are zero
        if (!vB) accB[td] = make_float4(0, 0, 0, 0);
        Lds[td][t] = accA[td];        // local chunk A = lr*16+col4 = t
        Lds[td][t + 256] = accB[td];  // local chunk B
    }
    __syncthreads();   // the ONE barrier per block

    // ---- phase 2: TD epilogues (verbatim R4) ----
    const bool sA = (lr >= 1);                 // owns output row gA
    const bool sB = (lr <= 14);                // owns output row gB
    const int iuA = (lr == 0) ? t : t - 16;    // clamp (discarded anyway)
    const int idB = (lr == 15) ? t + 256 : t + 272;
    const int oA = gA * 16 + col4;
    const int oB = gB * 16 + col4;

#pragma unroll
    for (int td = 0; td < TD; ++td) {
        const int dout = d0 + td;

        // chunk A vertical 3-tap
        const float4 uA = Lds[td][iuA];
        const float4 mA = Lds[td][t];
        const float4 dA = Lds[td][t + 16];     // lr=15 -> chunk B row 16: valid
        float4 VA;
        VA.x = uA.x + mA.x + dA.x; VA.y = uA.y + mA.y + dA.y;
        VA.z = uA.z + mA.z + dA.z; VA.w = uA.w + mA.w + dA.w;
        float4 rA = hsum3(VA, col4);

        // chunk B vertical 3-tap
        const float4 uB = Lds[td][t + 240];    // chunk A row lr+15: valid
        const float4 mB = Lds[td][t + 256];
        const float4 dB = Lds[td][idB];
        float4 VB;
        VB.x = uB.x + mB.x + dB.x; VB.y = uB.y + mB.y + dB.y;
        VB.z = uB.z + mB.z + dB.z; VB.w = uB.w + mB.w + dB.w;
        float4 rB = hsum3(VB, col4);

        rA.x = 0.25f * (rA.x + bbA.x); rA.y = 0.25f * (rA.y + bbA.y);
        rA.z = 0.25f * (rA.z + bbA.z); rA.w = 0.25f * (rA.w + bbA.w);
        rB.x = 0.25f * (rB.x + bbB.x); rB.y = 0.25f * (rB.y + bbB.y);
        rB.z = 0.25f * (rB.z + bbB.z); rB.w = 0.25f * (rB.w + bbB.w);
        rA.x = (rA.x > 0.f) ? rA.x : 0.2f * rA.x;
        rA.y = (rA.y > 0.f) ? rA.y : 0.2f * rA.y;
        rA.z = (rA.z > 0.f) ? rA.z : 0.2f * rA.z;
        rA.w = (rA.w > 0.f) ? rA.w : 0.2f * rA.w;
        rB.x = (rB.x > 0.f) ? rB.x : 0.2f * rB.x;
        rB.y = (rB.y > 0.f) ? rB.y : 0.2f * rB.y;
        rB.z = (rB.z > 0.f) ? rB.z : 0.2f * rB.z;
        rB.w = (rB.w > 0.f) ? rB.w : 0.2f * rB.w;

        if (dout < Dout_) {
            float4* od4 = (float4*)(ob + (size_t)dout * PLANE);
            if (sA) od4[oA] = rA;
            if (sB) od4[oB] = rB;
        }
    }
}

extern "C" void kernel_launch(void* const* d_in, const int* in_sizes, int n_in,
                              void* d_out, int out_size, void* d_ws, size_t ws_size,
                              hipStream_t stream) {
    const float* in = (const float*)d_in[0];
    const float* wt = (const float*)d_in[1];
    const float* bs = (const float*)d_in[2];
    float* out = (float*)d_out;

    float* s2 = (float*)d_ws;
    float* bb = s2 + S2_FLOATS;

    k_prep<<<dim3(NS2 + F_), dim3(256), 0, stream>>>(in, bs, s2, bb);
    k_main<<<dim3(B_ * F_ * NTILE * 2), dim3(256), 0, stream>>>(s2, wt, bb, out);
}